// Round 19
// baseline (271.578 us; speedup 1.0000x reference)
//
#include <hip/hip_runtime.h>
#include <hip/hip_bf16.h>

// Problem constants (from reference setup_inputs)
#define BB 4
#define NN 10000
#define CIN 512
#define H1 256
#define H2 128
#define TT 64
#define KK 10
#define SLOTS 48   // fixed entry slots per node (dv ~ Poisson(10); P(dv>48) ~ 1e-16)

struct Perm { int p[9]; };

// ---------------- host: exact numpy RandomState(0).permutation(19)[:9] ----------------
static void numpy_perm19(int* perm_out) {
    unsigned int mt[624];
    int mti;
    mt[0] = 0u;
    for (mti = 1; mti < 624; ++mti)
        mt[mti] = (unsigned int)(1812433253u * (mt[mti - 1] ^ (mt[mti - 1] >> 30)) + (unsigned int)mti);
    mti = 624;
    auto genrand = [&]() -> unsigned int {
        if (mti >= 624) {
            for (int kk = 0; kk < 624; ++kk) {
                unsigned int y = (mt[kk] & 0x80000000u) | (mt[(kk + 1) % 624] & 0x7fffffffu);
                mt[kk] = mt[(kk + 397) % 624] ^ (y >> 1) ^ ((y & 1u) ? 2567483615u : 0u);
            }
            mti = 0;
        }
        unsigned int y = mt[mti++];
        y ^= y >> 11;
        y ^= (y << 7) & 2636928640u;
        y ^= (y << 15) & 4022730752u;
        y ^= y >> 18;
        return y;
    };
    auto rk_interval = [&](unsigned int mx) -> unsigned int {
        if (mx == 0) return 0;
        unsigned int mask = mx;
        mask |= mask >> 1; mask |= mask >> 2; mask |= mask >> 4;
        mask |= mask >> 8; mask |= mask >> 16;
        unsigned int value;
        while ((value = (genrand() & mask)) > mx) {}
        return value;
    };
    int arr[19];
    for (int i = 0; i < 19; ++i) arr[i] = i;
    for (int i = 18; i >= 1; --i) {
        unsigned int j = rk_interval((unsigned int)i);
        int t = arr[j]; arr[j] = arr[i]; arr[i] = t;
    }
    for (int i = 0; i < 9; ++i) perm_out[i] = arr[i];
}

// ---------------- bf16 helpers ----------------
typedef __attribute__((ext_vector_type(8))) short bf16x8;
typedef __attribute__((ext_vector_type(4))) float f32x4;

__device__ __forceinline__ short f2bf(float f) {
    unsigned u = __float_as_uint(f);
    u = u + 0x7FFFu + ((u >> 16) & 1u);
    return (short)(u >> 16);
}
__device__ __forceinline__ float bf2f(short s) {
    return __uint_as_float(((unsigned)(unsigned short)s) << 16);
}
__device__ __forceinline__ void acc2(float& a, float& b, unsigned u) {
    a += __uint_as_float(u << 16);
    b += __uint_as_float(u & 0xffff0000u);
}
__device__ __forceinline__ unsigned pack2(float a, float b) {
    return (((unsigned)(unsigned short)f2bf(b)) << 16) | (unsigned)(unsigned short)f2bf(a);
}
// bijective XCD-aware block swizzle (m204 variant)
__device__ __forceinline__ int xcd_swz(int bid, int nwg) {
    int q = nwg >> 3, r = nwg & 7;
    int x = bid & 7, j = bid >> 3;
    return (x < r ? x * (q + 1) : r * (q + 1) + (x - r) * q) + j;
}

// ---- prep: convert both weights to [N][K] bf16, zero meanbuf, cursor, done ----
__global__ __launch_bounds__(256) void prep_w(const float* __restrict__ W0, const float* __restrict__ W1,
                                              short* __restrict__ W0t, short* __restrict__ W1t,
                                              float* __restrict__ meanbuf, int* __restrict__ cursor,
                                              int* __restrict__ done) {
    __shared__ short sh[32][36];               // [n][k], padded
    const int bid = blockIdx.x;
    {   // zero cursor (M=40000 <= 160*256=40960)
        int gi = bid * 256 + threadIdx.x;
        if (gi < BB * NN) cursor[gi] = 0;
    }
    if (bid == 0) {
        meanbuf[threadIdx.x] = 0.f;
        meanbuf[threadIdx.x + 256] = 0.f;      // BB*H2 = 512
        if (threadIdx.x == 0) *done = 0;
    }
    const float* W;
    short* Wt;
    int K, N, k0, n0;
    if (bid < 128) {
        W = W0; Wt = W0t; K = CIN; N = H1;
        k0 = (bid & 15) * 32; n0 = (bid >> 4) * 32;
    } else {
        int t = bid - 128;
        W = W1; Wt = W1t; K = H1; N = H2;
        k0 = (t & 7) * 32; n0 = (t >> 3) * 32;
    }
    const int kr = threadIdx.x >> 3, c4 = (threadIdx.x & 7) * 4;
    float4 w = *(const float4*)&W[(long)(k0 + kr) * N + n0 + c4];
    sh[c4 + 0][kr] = f2bf(w.x);
    sh[c4 + 1][kr] = f2bf(w.y);
    sh[c4 + 2][kr] = f2bf(w.z);
    sh[c4 + 3][kr] = f2bf(w.w);
    __syncthreads();
    const int nr = threadIdx.x >> 3;
    short4 h4;
    h4.x = sh[nr][c4]; h4.y = sh[nr][c4 + 1]; h4.z = sh[nr][c4 + 2]; h4.w = sh[nr][c4 + 3];
    *(short4*)&Wt[(long)(n0 + nr) * K + k0 + c4] = h4;
}

// ---------------- GEMM1 + fill_entries fused (independent work, one launch) --------------
#define GB1 625
#define FB  1563   // ceil(400000/256)
__global__ __launch_bounds__(256) void gemm1_fill(const float* __restrict__ A,
                                                  const short* __restrict__ Bt,
                                                  unsigned short* __restrict__ Cb,
                                                  const int* __restrict__ nn, Perm perm,
                                                  int* __restrict__ cursor, int* __restrict__ entries) {
    __shared__ short Ah[2][64][72];            // 144B row stride
    if (blockIdx.x >= GB1) {
        // ---- fill_entries part ----
        int j = (blockIdx.x - GB1) * 256 + threadIdx.x;   // over B*N*K
        if (j < BB * NN * KK) {
            int eg = j / KK, slot = j - eg * KK;
            int b = eg / NN, e = eg - b * NN;
            int node = (slot == 0) ? e : nn[(long)eg * (2 * KK - 1) + perm.p[slot - 1]];
            int g = b * NN + node;
            int pos = atomicAdd(&cursor[g], 1);
            if (pos < SLOTS) entries[(long)g * SLOTS + pos] = eg;
        }
        return;
    }
    // ---- gemm1 part ----
    const int tid = threadIdx.x, lane = tid & 63, wid = tid >> 6;
    const int l15 = lane & 15, lq = lane >> 4;
    const long r0 = (long)blockIdx.x * 64;
    const int cbase = wid * 64;
    f32x4 acc[4][4] = {};
    const int srow = tid >> 2, ssub = tid & 3;   // 64 rows x 4 chunks of 16 floats
    const float* ap = &A[(r0 + srow) * CIN + ssub * 16];
    const short* bp[4];
#pragma unroll
    for (int n = 0; n < 4; ++n) bp[n] = &Bt[(long)(cbase + n * 16 + l15) * CIN + lq * 8];

    float4 pa[4];
#pragma unroll
    for (int j = 0; j < 4; ++j) pa[j] = *(const float4*)(ap + j * 4);
    bf16x8 bh[8];                                // [n*2+kk]
#pragma unroll
    for (int n = 0; n < 4; ++n)
#pragma unroll
        for (int kk = 0; kk < 2; ++kk) bh[n * 2 + kk] = *(const bf16x8*)(bp[n] + kk * 32);
#pragma unroll
    for (int j = 0; j < 4; ++j) {
        short4 h;
        h.x = f2bf(pa[j].x); h.y = f2bf(pa[j].y); h.z = f2bf(pa[j].z); h.w = f2bf(pa[j].w);
        *(short4*)&Ah[0][srow][ssub * 16 + j * 4] = h;
    }
#pragma unroll
    for (int j = 0; j < 4; ++j) pa[j] = *(const float4*)(ap + 64 + j * 4);
    __syncthreads();

    int cur = 0;
    for (int k0 = 0; k0 < CIN; k0 += 64) {       // 8 steps
        const int kn = k0 + 64;
        bf16x8 bhn[8];
        if (kn < CIN) {
#pragma unroll
            for (int n = 0; n < 4; ++n)
#pragma unroll
                for (int kk = 0; kk < 2; ++kk)
                    bhn[n * 2 + kk] = *(const bf16x8*)(bp[n] + kn + kk * 32);
#pragma unroll
            for (int j = 0; j < 4; ++j) {
                short4 h;
                h.x = f2bf(pa[j].x); h.y = f2bf(pa[j].y); h.z = f2bf(pa[j].z); h.w = f2bf(pa[j].w);
                *(short4*)&Ah[cur ^ 1][srow][ssub * 16 + j * 4] = h;
            }
            if (kn + 64 < CIN) {
#pragma unroll
                for (int j = 0; j < 4; ++j) pa[j] = *(const float4*)(ap + kn + 64 + j * 4);
            }
        }
#pragma unroll
        for (int kk = 0; kk < 2; ++kk) {
            bf16x8 af[4];
#pragma unroll
            for (int m = 0; m < 4; ++m)
                af[m] = *(const bf16x8*)&Ah[cur][m * 16 + l15][kk * 32 + lq * 8];
#pragma unroll
            for (int m = 0; m < 4; ++m)
#pragma unroll
                for (int n = 0; n < 4; ++n)
                    acc[m][n] = __builtin_amdgcn_mfma_f32_16x16x32_bf16(af[m], bh[n * 2 + kk], acc[m][n], 0, 0, 0);
        }
#pragma unroll
        for (int i = 0; i < 8; ++i) bh[i] = bhn[i];
        __syncthreads();
        cur ^= 1;
    }
#pragma unroll
    for (int m = 0; m < 4; ++m)
#pragma unroll
        for (int n = 0; n < 4; ++n)
#pragma unroll
            for (int j = 0; j < 4; ++j) {
                long row = r0 + m * 16 + lq * 4 + j;
                int col = cbase + n * 16 + l15;
                Cb[row * H1 + col] = (unsigned short)f2bf(acc[m][n][j]);
            }
}

// ---------------- GEMM2: Cb[M][128] bf16 = A[M][256] bf16 @ Wt1 (BM=64, BK=64) -----------
__global__ __launch_bounds__(256) void gemm2(const unsigned short* __restrict__ A,
                                             const short* __restrict__ Bt,
                                             unsigned short* __restrict__ Cb) {
    __shared__ short As[2][64][72];
    const int tid = threadIdx.x, lane = tid & 63, wid = tid >> 6;
    const int l15 = lane & 15, lq = lane >> 4;
    const long r0 = (long)blockIdx.x * 64;
    const int cbase = wid * 32;
    f32x4 acc[4][2] = {};
    const int srow = tid >> 2, ssub = tid & 3;   // 64 rows x 4 chunks of 16 shorts
    const unsigned short* ap = &A[(r0 + srow) * H1 + ssub * 16];
    const short* bp[2];
#pragma unroll
    for (int n = 0; n < 2; ++n) bp[n] = &Bt[(long)(cbase + n * 16 + l15) * H1 + lq * 8];

    bf16x8 pre[2];
#pragma unroll
    for (int j = 0; j < 2; ++j) pre[j] = *(const bf16x8*)(ap + j * 8);
    bf16x8 bh[4];                                // [n*2+kk]
#pragma unroll
    for (int n = 0; n < 2; ++n)
#pragma unroll
        for (int kk = 0; kk < 2; ++kk) bh[n * 2 + kk] = *(const bf16x8*)(bp[n] + kk * 32);
#pragma unroll
    for (int j = 0; j < 2; ++j) *(bf16x8*)&As[0][srow][ssub * 16 + j * 8] = pre[j];
#pragma unroll
    for (int j = 0; j < 2; ++j) pre[j] = *(const bf16x8*)(ap + 64 + j * 8);
    __syncthreads();

    int cur = 0;
    for (int k0 = 0; k0 < H1; k0 += 64) {        // 4 steps
        const int kn = k0 + 64;
        bf16x8 bhn[4];
        if (kn < H1) {
#pragma unroll
            for (int n = 0; n < 2; ++n)
#pragma unroll
                for (int kk = 0; kk < 2; ++kk)
                    bhn[n * 2 + kk] = *(const bf16x8*)(bp[n] + kn + kk * 32);
#pragma unroll
            for (int j = 0; j < 2; ++j) *(bf16x8*)&As[cur ^ 1][srow][ssub * 16 + j * 8] = pre[j];
            if (kn + 64 < H1) {
#pragma unroll
                for (int j = 0; j < 2; ++j) pre[j] = *(const bf16x8*)(ap + kn + 64 + j * 8);
            }
        }
#pragma unroll
        for (int kk = 0; kk < 2; ++kk) {
            bf16x8 af[4];
#pragma unroll
            for (int m = 0; m < 4; ++m)
                af[m] = *(const bf16x8*)&As[cur][m * 16 + l15][kk * 32 + lq * 8];
#pragma unroll
            for (int m = 0; m < 4; ++m)
#pragma unroll
                for (int n = 0; n < 2; ++n)
                    acc[m][n] = __builtin_amdgcn_mfma_f32_16x16x32_bf16(af[m], bh[n * 2 + kk], acc[m][n], 0, 0, 0);
        }
#pragma unroll
        for (int i = 0; i < 4; ++i) bh[i] = bhn[i];
        __syncthreads();
        cur ^= 1;
    }
#pragma unroll
    for (int m = 0; m < 4; ++m)
#pragma unroll
        for (int n = 0; n < 2; ++n)
#pragma unroll
            for (int j = 0; j < 4; ++j) {
                long row = r0 + m * 16 + lq * 4 + j;
                int col = cbase + n * 16 + l15;
                Cb[row * H2 + col] = (unsigned short)f2bf(acc[m][n][j]);
            }
}

// ---- edge_ef for H1, channel-halved: grid 2*(M/16); XCDs 0-3 -> half 0, 4-7 -> half 1 ----
__global__ __launch_bounds__(256) void edge_ef_h1(const unsigned short* __restrict__ y,
                                                  const int* __restrict__ nn, Perm perm,
                                                  unsigned short* __restrict__ ef) {
    const int G = (BB * NN) / 16;         // 2500 blocks per half
    const int lb0 = xcd_swz(blockIdx.x, gridDim.x);
    const int half = lb0 / G;
    const int lb = lb0 - half * G;
    const int koff = half * (H1 / 2);     // 0 or 128 channels
    const int tid = threadIdx.x;
    const int lane = tid & 63, wv = tid >> 6;
    const int sub = lane >> 4, lr = lane & 15;
    const int eg = (lb * 4 + wv) * 4 + sub;
    const int b = eg / NN, e = eg - b * NN;
    const int* row = nn + (long)eg * (2 * KK - 1);
    int idx[KK];
    idx[0] = e;
#pragma unroll
    for (int i = 1; i < KK; ++i) idx[i] = row[perm.p[i - 1]];
    const unsigned short* yb = y + (long)b * NN * H1 + koff;
    float s[8] = {};
#pragma unroll
    for (int i = 0; i < KK; ++i) {
        uint4 v = *(const uint4*)&yb[(long)idx[i] * H1 + lr * 8];
        acc2(s[0], s[1], v.x); acc2(s[2], s[3], v.y);
        acc2(s[4], s[5], v.z); acc2(s[6], s[7], v.w);
    }
    uint4 o;
    o.x = pack2(0.1f * s[0], 0.1f * s[1]);
    o.y = pack2(0.1f * s[2], 0.1f * s[3]);
    o.z = pack2(0.1f * s[4], 0.1f * s[5]);
    o.w = pack2(0.1f * s[6], 0.1f * s[7]);
    *(uint4*)&ef[(long)eg * H1 + koff + lr * 8] = o;
}

// ---- node_gather for H1, channel-halved (same partitioning as edge_ef_h1) ----
__global__ __launch_bounds__(256) void node_gather_h1(const unsigned short* __restrict__ ef,
                                                      const int* __restrict__ cursor,
                                                      const int* __restrict__ entries,
                                                      const float* __restrict__ bias,
                                                      unsigned short* __restrict__ out) {
    const int G = (BB * NN) / 16;
    const int lb0 = xcd_swz(blockIdx.x, gridDim.x);
    const int half = lb0 / G;
    const int lb = lb0 - half * G;
    const int koff = half * (H1 / 2);
    const int tid = threadIdx.x;
    const int lane = tid & 63, wv = tid >> 6;
    const int sub = lane >> 4, lr = lane & 15;
    const int g = (lb * 4 + wv) * 4 + sub;
    const int cnt = cursor[g];
    const long s0 = (long)g * SLOTS;
    const long s1 = s0 + cnt;
    float s[8] = {};
    long i = s0;
    for (; i + 3 < s1; i += 4) {                      // 4-deep MLP on scattered rows
        int e0 = entries[i], e1 = entries[i + 1], e2 = entries[i + 2], e3 = entries[i + 3];
        uint4 v0 = *(const uint4*)&ef[(long)e0 * H1 + koff + lr * 8];
        uint4 v1 = *(const uint4*)&ef[(long)e1 * H1 + koff + lr * 8];
        uint4 v2 = *(const uint4*)&ef[(long)e2 * H1 + koff + lr * 8];
        uint4 v3 = *(const uint4*)&ef[(long)e3 * H1 + koff + lr * 8];
        acc2(s[0], s[1], v0.x); acc2(s[2], s[3], v0.y);
        acc2(s[4], s[5], v0.z); acc2(s[6], s[7], v0.w);
        acc2(s[0], s[1], v1.x); acc2(s[2], s[3], v1.y);
        acc2(s[4], s[5], v1.z); acc2(s[6], s[7], v1.w);
        acc2(s[0], s[1], v2.x); acc2(s[2], s[3], v2.y);
        acc2(s[4], s[5], v2.z); acc2(s[6], s[7], v2.w);
        acc2(s[0], s[1], v3.x); acc2(s[2], s[3], v3.y);
        acc2(s[4], s[5], v3.z); acc2(s[6], s[7], v3.w);
    }
    for (; i < s1; ++i) {
        uint4 v = *(const uint4*)&ef[(long)entries[i] * H1 + koff + lr * 8];
        acc2(s[0], s[1], v.x); acc2(s[2], s[3], v.y);
        acc2(s[4], s[5], v.z); acc2(s[6], s[7], v.w);
    }
    const float inv = 1.f / (float)cnt;
    float4 bb0 = *(const float4*)&bias[koff + lr * 8];
    float4 bb1 = *(const float4*)&bias[koff + lr * 8 + 4];
    float bv[8] = {bb0.x, bb0.y, bb0.z, bb0.w, bb1.x, bb1.y, bb1.z, bb1.w};
    float o[8];
#pragma unroll
    for (int j = 0; j < 8; ++j) {
        float v = s[j] * inv + bv[j];
        o[j] = v >= 0.f ? v : 0.01f * v;
    }
    uint4 w;
    w.x = pack2(o[0], o[1]); w.y = pack2(o[2], o[3]);
    w.z = pack2(o[4], o[5]); w.w = pack2(o[6], o[7]);
    *(uint4*)&out[(long)g * H1 + koff + lr * 8] = w;
}

// ---------------- ef for H2 (full width; 2.55MB/batch already L2-fits) -------------------
__global__ __launch_bounds__(256) void edge_ef_h2(const unsigned short* __restrict__ y,
                                                  const int* __restrict__ nn, Perm perm,
                                                  unsigned short* __restrict__ ef) {
    constexpr int H = H2;
    const int lb = xcd_swz(blockIdx.x, gridDim.x);
    const int tid = threadIdx.x;
    const int lane = tid & 63, wv = tid >> 6;
    const int sub = lane >> 4, lr = lane & 15;
    const int eg = (lb * 4 + wv) * 4 + sub;
    const int b = eg / NN, e = eg - b * NN;
    const int* row = nn + (long)eg * (2 * KK - 1);
    int idx[KK];
    idx[0] = e;
#pragma unroll
    for (int i = 1; i < KK; ++i) idx[i] = row[perm.p[i - 1]];
    const unsigned short* yb = y + (long)b * NN * H;
    float s[8] = {};
#pragma unroll
    for (int i = 0; i < KK; ++i) {
        uint4 v = *(const uint4*)&yb[(long)idx[i] * H + lr * 8];
        acc2(s[0], s[1], v.x); acc2(s[2], s[3], v.y);
        acc2(s[4], s[5], v.z); acc2(s[6], s[7], v.w);
    }
    uint4 o;
    o.x = pack2(0.1f * s[0], 0.1f * s[1]);
    o.y = pack2(0.1f * s[2], 0.1f * s[3]);
    o.z = pack2(0.1f * s[4], 0.1f * s[5]);
    o.w = pack2(0.1f * s[6], 0.1f * s[7]);
    *(uint4*)&ef[(long)eg * H + lr * 8] = o;
}

// ---- layer-2 node gather FUSED with mean AND final FC (last-block-done) ----
__global__ __launch_bounds__(256) void node_gather_mean_fc(const unsigned short* __restrict__ ef,
                                                           const int* __restrict__ cursor,
                                                           const int* __restrict__ entries,
                                                           const float* __restrict__ bias,
                                                           float* __restrict__ meanbuf,
                                                           int* __restrict__ done,
                                                           const float* __restrict__ fcw,
                                                           const float* __restrict__ fcb,
                                                           float* __restrict__ out, float invN) {
    constexpr int H = H2;                 // 128
    const int lb = xcd_swz(blockIdx.x, gridDim.x);
    const int tid = threadIdx.x;
    const int lane = tid & 63, wv = tid >> 6;
    const int sub = lane >> 4, lr = lane & 15;
    const int g = (lb * 4 + wv) * 4 + sub;
    const int b = (lb * 16) / NN;         // whole block in one batch
    const int cnt = cursor[g];
    const long s0 = (long)g * SLOTS;
    const long s1 = s0 + cnt;
    float s[8] = {};
    long i = s0;
    for (; i + 3 < s1; i += 4) {
        int e0 = entries[i], e1 = entries[i + 1], e2 = entries[i + 2], e3 = entries[i + 3];
        uint4 v0 = *(const uint4*)&ef[(long)e0 * H + lr * 8];
        uint4 v1 = *(const uint4*)&ef[(long)e1 * H + lr * 8];
        uint4 v2 = *(const uint4*)&ef[(long)e2 * H + lr * 8];
        uint4 v3 = *(const uint4*)&ef[(long)e3 * H + lr * 8];
        acc2(s[0], s[1], v0.x); acc2(s[2], s[3], v0.y);
        acc2(s[4], s[5], v0.z); acc2(s[6], s[7], v0.w);
        acc2(s[0], s[1], v1.x); acc2(s[2], s[3], v1.y);
        acc2(s[4], s[5], v1.z); acc2(s[6], s[7], v1.w);
        acc2(s[0], s[1], v2.x); acc2(s[2], s[3], v2.y);
        acc2(s[4], s[5], v2.z); acc2(s[6], s[7], v2.w);
        acc2(s[0], s[1], v3.x); acc2(s[2], s[3], v3.y);
        acc2(s[4], s[5], v3.z); acc2(s[6], s[7], v3.w);
    }
    for (; i < s1; ++i) {
        uint4 v = *(const uint4*)&ef[(long)entries[i] * H + lr * 8];
        acc2(s[0], s[1], v.x); acc2(s[2], s[3], v.y);
        acc2(s[4], s[5], v.z); acc2(s[6], s[7], v.w);
    }
    const float inv = 1.f / (float)cnt;
    float4 bb0 = *(const float4*)&bias[lr * 8];
    float4 bb1 = *(const float4*)&bias[lr * 8 + 4];
    float bv[8] = {bb0.x, bb0.y, bb0.z, bb0.w, bb1.x, bb1.y, bb1.z, bb1.w};
    __shared__ float sm[16][128];
    const int rowid = tid >> 4;           // == wv*4 + sub
#pragma unroll
    for (int j = 0; j < 8; ++j) {
        float v = s[j] * inv + bv[j];
        sm[rowid][lr * 8 + j] = v >= 0.f ? v : 0.01f * v;
    }
    __syncthreads();
    if (tid < 128) {
        float acc = 0.f;
#pragma unroll
        for (int r = 0; r < 16; ++r) acc += sm[r][tid];
        atomicAdd(&meanbuf[b * H2 + tid], acc);
    }
    // ---- last-block: compute FC ----
    __threadfence();
    __shared__ int amlast;
    __syncthreads();
    if (tid == 0) amlast = (atomicAdd(done, 1) == (int)gridDim.x - 1) ? 1 : 0;
    __syncthreads();
    if (amlast) {
        __threadfence();
        int bb = tid / TT, t = tid % TT;   // 256 threads = 4 batches x 64 outputs
        float sfc = 0.f;
        for (int c = 0; c < H2; ++c) sfc += meanbuf[bb * H2 + c] * fcw[c * TT + t];
        out[tid] = sfc * invN + fcb[t];
    }
}

extern "C" void kernel_launch(void* const* d_in, const int* in_sizes, int n_in,
                              void* d_out, int out_size, void* d_ws, size_t ws_size,
                              hipStream_t stream) {
    const float* x      = (const float*)d_in[0];
    const int*   nn     = (const int*)d_in[1];
    const float* theta0 = (const float*)d_in[2];
    const float* b0     = (const float*)d_in[3];
    const float* theta1 = (const float*)d_in[4];
    const float* b1     = (const float*)d_in[5];
    const float* fcw    = (const float*)d_in[6];
    const float* fcb    = (const float*)d_in[7];
    float* out = (float*)d_out;

    Perm perm;
    numpy_perm19(perm.p);

    const long M = (long)BB * NN;                 // 40000

    unsigned short* bufY = (unsigned short*)d_ws;         // M*H1 bf16 (y / y1)
    unsigned short* bufE = bufY + M * H1;                 // M*H1 bf16 (ef)
    unsigned short* bufH = bufE + M * H1;                 // M*H1 bf16 (h1)
    short* W0t = (short*)(bufH + M * H1);                 // H1*CIN bf16
    short* W1t = W0t + (long)H1 * CIN;                    // H2*H1 bf16
    int*   cursor  = (int*)(W1t + (long)H2 * H1);         // M (doubles as dv counts)
    int*   entries = cursor + M;                          // M*SLOTS
    float* meanbuf = (float*)(entries + M * SLOTS);       // B*H2
    int*   done    = (int*)(meanbuf + BB * H2);           // 1

    // --- prep: convert weights + zero cursor/meanbuf/done ---
    prep_w<<<160, 256, 0, stream>>>(theta0, theta1, W0t, W1t, meanbuf, cursor, done);

    // --- layer 1 (gemm1 fused with slot-CSR fill; both depend only on prep_w) ---
    gemm1_fill<<<GB1 + FB, 256, 0, stream>>>(x, W0t, bufY, nn, perm, cursor, entries);
    edge_ef_h1<<<(int)(M / 16) * 2, 256, 0, stream>>>(bufY, nn, perm, bufE);
    node_gather_h1<<<(int)(M / 16) * 2, 256, 0, stream>>>(bufE, cursor, entries, b0, bufH);
    // h1 in bufH [M][256] bf16

    // --- layer 2 ---
    gemm2<<<(int)(M / 64), 256, 0, stream>>>(bufH, W1t, bufY);
    edge_ef_h2<<<(int)(M / 16), 256, 0, stream>>>(bufY, nn, perm, bufE);
    // fused node-gather + leaky + mean + FC (last block)
    node_gather_mean_fc<<<(int)(M / 16), 256, 0, stream>>>(bufE, cursor, entries, b1, meanbuf,
                                                           done, fcw, fcb, out, 1.0f / (float)NN);
}

// Round 20
// 133.363 us; speedup vs baseline: 2.0364x; 2.0364x over previous
//
#include <hip/hip_runtime.h>
#include <hip/hip_bf16.h>

// Problem constants (from reference setup_inputs)
#define BB 4
#define NN 10000
#define CIN 512
#define H1 256
#define H2 128
#define TT 64
#define KK 10
#define SLOTS 48   // fixed entry slots per node (dv ~ Poisson(10); P(dv>48) ~ 1e-16)

struct Perm { int p[9]; };

// ---------------- host: exact numpy RandomState(0).permutation(19)[:9] ----------------
static void numpy_perm19(int* perm_out) {
    unsigned int mt[624];
    int mti;
    mt[0] = 0u;
    for (mti = 1; mti < 624; ++mti)
        mt[mti] = (unsigned int)(1812433253u * (mt[mti - 1] ^ (mt[mti - 1] >> 30)) + (unsigned int)mti);
    mti = 624;
    auto genrand = [&]() -> unsigned int {
        if (mti >= 624) {
            for (int kk = 0; kk < 624; ++kk) {
                unsigned int y = (mt[kk] & 0x80000000u) | (mt[(kk + 1) % 624] & 0x7fffffffu);
                mt[kk] = mt[(kk + 397) % 624] ^ (y >> 1) ^ ((y & 1u) ? 2567483615u : 0u);
            }
            mti = 0;
        }
        unsigned int y = mt[mti++];
        y ^= y >> 11;
        y ^= (y << 7) & 2636928640u;
        y ^= (y << 15) & 4022730752u;
        y ^= y >> 18;
        return y;
    };
    auto rk_interval = [&](unsigned int mx) -> unsigned int {
        if (mx == 0) return 0;
        unsigned int mask = mx;
        mask |= mask >> 1; mask |= mask >> 2; mask |= mask >> 4;
        mask |= mask >> 8; mask |= mask >> 16;
        unsigned int value;
        while ((value = (genrand() & mask)) > mx) {}
        return value;
    };
    int arr[19];
    for (int i = 0; i < 19; ++i) arr[i] = i;
    for (int i = 18; i >= 1; --i) {
        unsigned int j = rk_interval((unsigned int)i);
        int t = arr[j]; arr[j] = arr[i]; arr[i] = t;
    }
    for (int i = 0; i < 9; ++i) perm_out[i] = arr[i];
}

// ---------------- bf16 helpers ----------------
typedef __attribute__((ext_vector_type(8))) short bf16x8;
typedef __attribute__((ext_vector_type(4))) float f32x4;

__device__ __forceinline__ short f2bf(float f) {
    unsigned u = __float_as_uint(f);
    u = u + 0x7FFFu + ((u >> 16) & 1u);
    return (short)(u >> 16);
}
__device__ __forceinline__ float bf2f(short s) {
    return __uint_as_float(((unsigned)(unsigned short)s) << 16);
}
__device__ __forceinline__ void acc2(float& a, float& b, unsigned u) {
    a += __uint_as_float(u << 16);
    b += __uint_as_float(u & 0xffff0000u);
}
__device__ __forceinline__ unsigned pack2(float a, float b) {
    return (((unsigned)(unsigned short)f2bf(b)) << 16) | (unsigned)(unsigned short)f2bf(a);
}
// bijective XCD-aware block swizzle (m204 variant)
__device__ __forceinline__ int xcd_swz(int bid, int nwg) {
    int q = nwg >> 3, r = nwg & 7;
    int x = bid & 7, j = bid >> 3;
    return (x < r ? x * (q + 1) : r * (q + 1) + (x - r) * q) + j;
}

// ---- prep: convert both weights to [N][K] bf16, zero meanbuf AND cursor ----
__global__ __launch_bounds__(256) void prep_w(const float* __restrict__ W0, const float* __restrict__ W1,
                                              short* __restrict__ W0t, short* __restrict__ W1t,
                                              float* __restrict__ meanbuf, int* __restrict__ cursor) {
    __shared__ short sh[32][36];               // [n][k], padded
    const int bid = blockIdx.x;
    {   // zero cursor (M=40000 <= 160*256=40960)
        int gi = bid * 256 + threadIdx.x;
        if (gi < BB * NN) cursor[gi] = 0;
    }
    if (bid == 0) {
        meanbuf[threadIdx.x] = 0.f;
        meanbuf[threadIdx.x + 256] = 0.f;      // BB*H2 = 512
    }
    const float* W;
    short* Wt;
    int K, N, k0, n0;
    if (bid < 128) {
        W = W0; Wt = W0t; K = CIN; N = H1;
        k0 = (bid & 15) * 32; n0 = (bid >> 4) * 32;
    } else {
        int t = bid - 128;
        W = W1; Wt = W1t; K = H1; N = H2;
        k0 = (t & 7) * 32; n0 = (t >> 3) * 32;
    }
    const int kr = threadIdx.x >> 3, c4 = (threadIdx.x & 7) * 4;
    float4 w = *(const float4*)&W[(long)(k0 + kr) * N + n0 + c4];
    sh[c4 + 0][kr] = f2bf(w.x);
    sh[c4 + 1][kr] = f2bf(w.y);
    sh[c4 + 2][kr] = f2bf(w.z);
    sh[c4 + 3][kr] = f2bf(w.w);
    __syncthreads();
    const int nr = threadIdx.x >> 3;
    short4 h4;
    h4.x = sh[nr][c4]; h4.y = sh[nr][c4 + 1]; h4.z = sh[nr][c4 + 2]; h4.w = sh[nr][c4 + 3];
    *(short4*)&Wt[(long)(n0 + nr) * K + k0 + c4] = h4;
}

// ---------------- GEMM1 + fill_entries fused (independent work, one launch) --------------
// blocks [0, GB1): GEMM1 Cb[M][256] = A[M][512] f32 @ Wt0 (BM=64, BK=64, dbuf, B-prefetch)
// blocks [GB1, GB1+FB): slot-CSR fill (atomic cursor + scattered entry store)
#define GB1 625
#define FB  1563   // ceil(400000/256)
__global__ __launch_bounds__(256) void gemm1_fill(const float* __restrict__ A,
                                                  const short* __restrict__ Bt,
                                                  unsigned short* __restrict__ Cb,
                                                  const int* __restrict__ nn, Perm perm,
                                                  int* __restrict__ cursor, int* __restrict__ entries) {
    __shared__ short Ah[2][64][72];            // 144B row stride
    if (blockIdx.x >= GB1) {
        // ---- fill_entries part ----
        int j = (blockIdx.x - GB1) * 256 + threadIdx.x;   // over B*N*K
        if (j < BB * NN * KK) {
            int eg = j / KK, slot = j - eg * KK;
            int b = eg / NN, e = eg - b * NN;
            int node = (slot == 0) ? e : nn[(long)eg * (2 * KK - 1) + perm.p[slot - 1]];
            int g = b * NN + node;
            int pos = atomicAdd(&cursor[g], 1);
            if (pos < SLOTS) entries[(long)g * SLOTS + pos] = eg;
        }
        return;
    }
    // ---- gemm1 part ----
    const int tid = threadIdx.x, lane = tid & 63, wid = tid >> 6;
    const int l15 = lane & 15, lq = lane >> 4;
    const long r0 = (long)blockIdx.x * 64;
    const int cbase = wid * 64;
    f32x4 acc[4][4] = {};
    const int srow = tid >> 2, ssub = tid & 3;   // 64 rows x 4 chunks of 16 floats
    const float* ap = &A[(r0 + srow) * CIN + ssub * 16];
    const short* bp[4];
#pragma unroll
    for (int n = 0; n < 4; ++n) bp[n] = &Bt[(long)(cbase + n * 16 + l15) * CIN + lq * 8];

    float4 pa[4];
#pragma unroll
    for (int j = 0; j < 4; ++j) pa[j] = *(const float4*)(ap + j * 4);
    bf16x8 bh[8];                                // [n*2+kk]
#pragma unroll
    for (int n = 0; n < 4; ++n)
#pragma unroll
        for (int kk = 0; kk < 2; ++kk) bh[n * 2 + kk] = *(const bf16x8*)(bp[n] + kk * 32);
#pragma unroll
    for (int j = 0; j < 4; ++j) {
        short4 h;
        h.x = f2bf(pa[j].x); h.y = f2bf(pa[j].y); h.z = f2bf(pa[j].z); h.w = f2bf(pa[j].w);
        *(short4*)&Ah[0][srow][ssub * 16 + j * 4] = h;
    }
#pragma unroll
    for (int j = 0; j < 4; ++j) pa[j] = *(const float4*)(ap + 64 + j * 4);
    __syncthreads();

    int cur = 0;
    for (int k0 = 0; k0 < CIN; k0 += 64) {       // 8 steps
        const int kn = k0 + 64;
        bf16x8 bhn[8];
        if (kn < CIN) {
#pragma unroll
            for (int n = 0; n < 4; ++n)
#pragma unroll
                for (int kk = 0; kk < 2; ++kk)
                    bhn[n * 2 + kk] = *(const bf16x8*)(bp[n] + kn + kk * 32);
#pragma unroll
            for (int j = 0; j < 4; ++j) {
                short4 h;
                h.x = f2bf(pa[j].x); h.y = f2bf(pa[j].y); h.z = f2bf(pa[j].z); h.w = f2bf(pa[j].w);
                *(short4*)&Ah[cur ^ 1][srow][ssub * 16 + j * 4] = h;
            }
            if (kn + 64 < CIN) {
#pragma unroll
                for (int j = 0; j < 4; ++j) pa[j] = *(const float4*)(ap + kn + 64 + j * 4);
            }
        }
#pragma unroll
        for (int kk = 0; kk < 2; ++kk) {
            bf16x8 af[4];
#pragma unroll
            for (int m = 0; m < 4; ++m)
                af[m] = *(const bf16x8*)&Ah[cur][m * 16 + l15][kk * 32 + lq * 8];
#pragma unroll
            for (int m = 0; m < 4; ++m)
#pragma unroll
                for (int n = 0; n < 4; ++n)
                    acc[m][n] = __builtin_amdgcn_mfma_f32_16x16x32_bf16(af[m], bh[n * 2 + kk], acc[m][n], 0, 0, 0);
        }
#pragma unroll
        for (int i = 0; i < 8; ++i) bh[i] = bhn[i];
        __syncthreads();
        cur ^= 1;
    }
#pragma unroll
    for (int m = 0; m < 4; ++m)
#pragma unroll
        for (int n = 0; n < 4; ++n)
#pragma unroll
            for (int j = 0; j < 4; ++j) {
                long row = r0 + m * 16 + lq * 4 + j;
                int col = cbase + n * 16 + l15;
                Cb[row * H1 + col] = (unsigned short)f2bf(acc[m][n][j]);
            }
}

// ---------------- GEMM2: Cb[M][128] bf16 = A[M][256] bf16 @ Wt1 (BM=64, BK=64) -----------
__global__ __launch_bounds__(256) void gemm2(const unsigned short* __restrict__ A,
                                             const short* __restrict__ Bt,
                                             unsigned short* __restrict__ Cb) {
    __shared__ short As[2][64][72];
    const int tid = threadIdx.x, lane = tid & 63, wid = tid >> 6;
    const int l15 = lane & 15, lq = lane >> 4;
    const long r0 = (long)blockIdx.x * 64;
    const int cbase = wid * 32;
    f32x4 acc[4][2] = {};
    const int srow = tid >> 2, ssub = tid & 3;   // 64 rows x 4 chunks of 16 shorts
    const unsigned short* ap = &A[(r0 + srow) * H1 + ssub * 16];
    const short* bp[2];
#pragma unroll
    for (int n = 0; n < 2; ++n) bp[n] = &Bt[(long)(cbase + n * 16 + l15) * H1 + lq * 8];

    bf16x8 pre[2];
#pragma unroll
    for (int j = 0; j < 2; ++j) pre[j] = *(const bf16x8*)(ap + j * 8);
    bf16x8 bh[4];                                // [n*2+kk]
#pragma unroll
    for (int n = 0; n < 2; ++n)
#pragma unroll
        for (int kk = 0; kk < 2; ++kk) bh[n * 2 + kk] = *(const bf16x8*)(bp[n] + kk * 32);
#pragma unroll
    for (int j = 0; j < 2; ++j) *(bf16x8*)&As[0][srow][ssub * 16 + j * 8] = pre[j];
#pragma unroll
    for (int j = 0; j < 2; ++j) pre[j] = *(const bf16x8*)(ap + 64 + j * 8);
    __syncthreads();

    int cur = 0;
    for (int k0 = 0; k0 < H1; k0 += 64) {        // 4 steps
        const int kn = k0 + 64;
        bf16x8 bhn[4];
        if (kn < H1) {
#pragma unroll
            for (int n = 0; n < 2; ++n)
#pragma unroll
                for (int kk = 0; kk < 2; ++kk)
                    bhn[n * 2 + kk] = *(const bf16x8*)(bp[n] + kn + kk * 32);
#pragma unroll
            for (int j = 0; j < 2; ++j) *(bf16x8*)&As[cur ^ 1][srow][ssub * 16 + j * 8] = pre[j];
            if (kn + 64 < H1) {
#pragma unroll
                for (int j = 0; j < 2; ++j) pre[j] = *(const bf16x8*)(ap + kn + 64 + j * 8);
            }
        }
#pragma unroll
        for (int kk = 0; kk < 2; ++kk) {
            bf16x8 af[4];
#pragma unroll
            for (int m = 0; m < 4; ++m)
                af[m] = *(const bf16x8*)&As[cur][m * 16 + l15][kk * 32 + lq * 8];
#pragma unroll
            for (int m = 0; m < 4; ++m)
#pragma unroll
                for (int n = 0; n < 2; ++n)
                    acc[m][n] = __builtin_amdgcn_mfma_f32_16x16x32_bf16(af[m], bh[n * 2 + kk], acc[m][n], 0, 0, 0);
        }
#pragma unroll
        for (int i = 0; i < 4; ++i) bh[i] = bhn[i];
        __syncthreads();
        cur ^= 1;
    }
#pragma unroll
    for (int m = 0; m < 4; ++m)
#pragma unroll
        for (int n = 0; n < 2; ++n)
#pragma unroll
            for (int j = 0; j < 4; ++j) {
                long row = r0 + m * 16 + lq * 4 + j;
                int col = cbase + n * 16 + l15;
                Cb[row * H2 + col] = (unsigned short)f2bf(acc[m][n][j]);
            }
}

// ---- edge_ef for H1, channel-halved: grid 2*(M/16); XCDs 0-3 -> half 0, 4-7 -> half 1 ----
__global__ __launch_bounds__(256) void edge_ef_h1(const unsigned short* __restrict__ y,
                                                  const int* __restrict__ nn, Perm perm,
                                                  unsigned short* __restrict__ ef) {
    const int G = (BB * NN) / 16;         // 2500 blocks per half
    const int lb0 = xcd_swz(blockIdx.x, gridDim.x);
    const int half = lb0 / G;
    const int lb = lb0 - half * G;
    const int koff = half * (H1 / 2);     // 0 or 128 channels
    const int tid = threadIdx.x;
    const int lane = tid & 63, wv = tid >> 6;
    const int sub = lane >> 4, lr = lane & 15;
    const int eg = (lb * 4 + wv) * 4 + sub;
    const int b = eg / NN, e = eg - b * NN;
    const int* row = nn + (long)eg * (2 * KK - 1);
    int idx[KK];
    idx[0] = e;
#pragma unroll
    for (int i = 1; i < KK; ++i) idx[i] = row[perm.p[i - 1]];
    const unsigned short* yb = y + (long)b * NN * H1 + koff;
    float s[8] = {};
#pragma unroll
    for (int i = 0; i < KK; ++i) {
        uint4 v = *(const uint4*)&yb[(long)idx[i] * H1 + lr * 8];
        acc2(s[0], s[1], v.x); acc2(s[2], s[3], v.y);
        acc2(s[4], s[5], v.z); acc2(s[6], s[7], v.w);
    }
    uint4 o;
    o.x = pack2(0.1f * s[0], 0.1f * s[1]);
    o.y = pack2(0.1f * s[2], 0.1f * s[3]);
    o.z = pack2(0.1f * s[4], 0.1f * s[5]);
    o.w = pack2(0.1f * s[6], 0.1f * s[7]);
    *(uint4*)&ef[(long)eg * H1 + koff + lr * 8] = o;
}

// ---- node_gather for H1, channel-halved (same partitioning as edge_ef_h1) ----
__global__ __launch_bounds__(256) void node_gather_h1(const unsigned short* __restrict__ ef,
                                                      const int* __restrict__ cursor,
                                                      const int* __restrict__ entries,
                                                      const float* __restrict__ bias,
                                                      unsigned short* __restrict__ out) {
    const int G = (BB * NN) / 16;
    const int lb0 = xcd_swz(blockIdx.x, gridDim.x);
    const int half = lb0 / G;
    const int lb = lb0 - half * G;
    const int koff = half * (H1 / 2);
    const int tid = threadIdx.x;
    const int lane = tid & 63, wv = tid >> 6;
    const int sub = lane >> 4, lr = lane & 15;
    const int g = (lb * 4 + wv) * 4 + sub;
    const int cnt = cursor[g];
    const long s0 = (long)g * SLOTS;
    const long s1 = s0 + cnt;
    float s[8] = {};
    long i = s0;
    for (; i + 3 < s1; i += 4) {                      // 4-deep MLP on scattered rows
        int e0 = entries[i], e1 = entries[i + 1], e2 = entries[i + 2], e3 = entries[i + 3];
        uint4 v0 = *(const uint4*)&ef[(long)e0 * H1 + koff + lr * 8];
        uint4 v1 = *(const uint4*)&ef[(long)e1 * H1 + koff + lr * 8];
        uint4 v2 = *(const uint4*)&ef[(long)e2 * H1 + koff + lr * 8];
        uint4 v3 = *(const uint4*)&ef[(long)e3 * H1 + koff + lr * 8];
        acc2(s[0], s[1], v0.x); acc2(s[2], s[3], v0.y);
        acc2(s[4], s[5], v0.z); acc2(s[6], s[7], v0.w);
        acc2(s[0], s[1], v1.x); acc2(s[2], s[3], v1.y);
        acc2(s[4], s[5], v1.z); acc2(s[6], s[7], v1.w);
        acc2(s[0], s[1], v2.x); acc2(s[2], s[3], v2.y);
        acc2(s[4], s[5], v2.z); acc2(s[6], s[7], v2.w);
        acc2(s[0], s[1], v3.x); acc2(s[2], s[3], v3.y);
        acc2(s[4], s[5], v3.z); acc2(s[6], s[7], v3.w);
    }
    for (; i < s1; ++i) {
        uint4 v = *(const uint4*)&ef[(long)entries[i] * H1 + koff + lr * 8];
        acc2(s[0], s[1], v.x); acc2(s[2], s[3], v.y);
        acc2(s[4], s[5], v.z); acc2(s[6], s[7], v.w);
    }
    const float inv = 1.f / (float)cnt;
    float4 bb0 = *(const float4*)&bias[koff + lr * 8];
    float4 bb1 = *(const float4*)&bias[koff + lr * 8 + 4];
    float bv[8] = {bb0.x, bb0.y, bb0.z, bb0.w, bb1.x, bb1.y, bb1.z, bb1.w};
    float o[8];
#pragma unroll
    for (int j = 0; j < 8; ++j) {
        float v = s[j] * inv + bv[j];
        o[j] = v >= 0.f ? v : 0.01f * v;
    }
    uint4 w;
    w.x = pack2(o[0], o[1]); w.y = pack2(o[2], o[3]);
    w.z = pack2(o[4], o[5]); w.w = pack2(o[6], o[7]);
    *(uint4*)&out[(long)g * H1 + koff + lr * 8] = w;
}

// ---------------- ef for H2 (full width; 2.55MB/batch already L2-fits) -------------------
__global__ __launch_bounds__(256) void edge_ef_h2(const unsigned short* __restrict__ y,
                                                  const int* __restrict__ nn, Perm perm,
                                                  unsigned short* __restrict__ ef) {
    constexpr int H = H2;
    const int lb = xcd_swz(blockIdx.x, gridDim.x);
    const int tid = threadIdx.x;
    const int lane = tid & 63, wv = tid >> 6;
    const int sub = lane >> 4, lr = lane & 15;
    const int eg = (lb * 4 + wv) * 4 + sub;
    const int b = eg / NN, e = eg - b * NN;
    const int* row = nn + (long)eg * (2 * KK - 1);
    int idx[KK];
    idx[0] = e;
#pragma unroll
    for (int i = 1; i < KK; ++i) idx[i] = row[perm.p[i - 1]];
    const unsigned short* yb = y + (long)b * NN * H;
    float s[8] = {};
#pragma unroll
    for (int i = 0; i < KK; ++i) {
        uint4 v = *(const uint4*)&yb[(long)idx[i] * H + lr * 8];
        acc2(s[0], s[1], v.x); acc2(s[2], s[3], v.y);
        acc2(s[4], s[5], v.z); acc2(s[6], s[7], v.w);
    }
    uint4 o;
    o.x = pack2(0.1f * s[0], 0.1f * s[1]);
    o.y = pack2(0.1f * s[2], 0.1f * s[3]);
    o.z = pack2(0.1f * s[4], 0.1f * s[5]);
    o.w = pack2(0.1f * s[6], 0.1f * s[7]);
    *(uint4*)&ef[(long)eg * H + lr * 8] = o;
}

// ---- layer-2 node gather FUSED with mean: no h2 write; LDS-reduce + atomics to meanbuf ----
__global__ __launch_bounds__(256) void node_gather_mean(const unsigned short* __restrict__ ef,
                                                        const int* __restrict__ cursor,
                                                        const int* __restrict__ entries,
                                                        const float* __restrict__ bias,
                                                        float* __restrict__ meanbuf) {
    constexpr int H = H2;                 // 128
    const int lb = xcd_swz(blockIdx.x, gridDim.x);
    const int tid = threadIdx.x;
    const int lane = tid & 63, wv = tid >> 6;
    const int sub = lane >> 4, lr = lane & 15;
    const int g = (lb * 4 + wv) * 4 + sub;
    const int b = (lb * 16) / NN;         // whole block in one batch
    const int cnt = cursor[g];
    const long s0 = (long)g * SLOTS;
    const long s1 = s0 + cnt;
    float s[8] = {};
    long i = s0;
    for (; i + 3 < s1; i += 4) {
        int e0 = entries[i], e1 = entries[i + 1], e2 = entries[i + 2], e3 = entries[i + 3];
        uint4 v0 = *(const uint4*)&ef[(long)e0 * H + lr * 8];
        uint4 v1 = *(const uint4*)&ef[(long)e1 * H + lr * 8];
        uint4 v2 = *(const uint4*)&ef[(long)e2 * H + lr * 8];
        uint4 v3 = *(const uint4*)&ef[(long)e3 * H + lr * 8];
        acc2(s[0], s[1], v0.x); acc2(s[2], s[3], v0.y);
        acc2(s[4], s[5], v0.z); acc2(s[6], s[7], v0.w);
        acc2(s[0], s[1], v1.x); acc2(s[2], s[3], v1.y);
        acc2(s[4], s[5], v1.z); acc2(s[6], s[7], v1.w);
        acc2(s[0], s[1], v2.x); acc2(s[2], s[3], v2.y);
        acc2(s[4], s[5], v2.z); acc2(s[6], s[7], v2.w);
        acc2(s[0], s[1], v3.x); acc2(s[2], s[3], v3.y);
        acc2(s[4], s[5], v3.z); acc2(s[6], s[7], v3.w);
    }
    for (; i < s1; ++i) {
        uint4 v = *(const uint4*)&ef[(long)entries[i] * H + lr * 8];
        acc2(s[0], s[1], v.x); acc2(s[2], s[3], v.y);
        acc2(s[4], s[5], v.z); acc2(s[6], s[7], v.w);
    }
    const float inv = 1.f / (float)cnt;
    float4 bb0 = *(const float4*)&bias[lr * 8];
    float4 bb1 = *(const float4*)&bias[lr * 8 + 4];
    float bv[8] = {bb0.x, bb0.y, bb0.z, bb0.w, bb1.x, bb1.y, bb1.z, bb1.w};
    __shared__ float sm[16][128];
    const int rowid = tid >> 4;           // == wv*4 + sub
#pragma unroll
    for (int j = 0; j < 8; ++j) {
        float v = s[j] * inv + bv[j];
        sm[rowid][lr * 8 + j] = v >= 0.f ? v : 0.01f * v;
    }
    __syncthreads();
    if (tid < 128) {
        float acc = 0.f;
#pragma unroll
        for (int r = 0; r < 16; ++r) acc += sm[r][tid];
        atomicAdd(&meanbuf[b * H2 + tid], acc);
    }
}

// ---------------- final FC ----------------
__global__ void fc_k(const float* __restrict__ meanbuf, const float* __restrict__ fcw,
                     const float* __restrict__ fcb, float* __restrict__ out, float invN) {
    int tid = threadIdx.x;   // 256
    int b = tid / TT, t = tid % TT;
    float s = 0.f;
    for (int c = 0; c < H2; ++c) s += meanbuf[b * H2 + c] * fcw[c * TT + t];
    out[tid] = s * invN + fcb[t];
}

extern "C" void kernel_launch(void* const* d_in, const int* in_sizes, int n_in,
                              void* d_out, int out_size, void* d_ws, size_t ws_size,
                              hipStream_t stream) {
    const float* x      = (const float*)d_in[0];
    const int*   nn     = (const int*)d_in[1];
    const float* theta0 = (const float*)d_in[2];
    const float* b0     = (const float*)d_in[3];
    const float* theta1 = (const float*)d_in[4];
    const float* b1     = (const float*)d_in[5];
    const float* fcw    = (const float*)d_in[6];
    const float* fcb    = (const float*)d_in[7];
    float* out = (float*)d_out;

    Perm perm;
    numpy_perm19(perm.p);

    const long M = (long)BB * NN;                 // 40000

    unsigned short* bufY = (unsigned short*)d_ws;         // M*H1 bf16 (y / y1)
    unsigned short* bufE = bufY + M * H1;                 // M*H1 bf16 (ef)
    unsigned short* bufH = bufE + M * H1;                 // M*H1 bf16 (h1)
    short* W0t = (short*)(bufH + M * H1);                 // H1*CIN bf16
    short* W1t = W0t + (long)H1 * CIN;                    // H2*H1 bf16
    int*   cursor  = (int*)(W1t + (long)H2 * H1);         // M (doubles as dv counts)
    int*   entries = cursor + M;                          // M*SLOTS
    float* meanbuf = (float*)(entries + M * SLOTS);       // B*H2

    // --- prep: convert weights + zero cursor/meanbuf ---
    prep_w<<<160, 256, 0, stream>>>(theta0, theta1, W0t, W1t, meanbuf, cursor);

    // --- layer 1 (gemm1 fused with slot-CSR fill; both depend only on prep_w) ---
    gemm1_fill<<<GB1 + FB, 256, 0, stream>>>(x, W0t, bufY, nn, perm, cursor, entries);
    edge_ef_h1<<<(int)(M / 16) * 2, 256, 0, stream>>>(bufY, nn, perm, bufE);
    node_gather_h1<<<(int)(M / 16) * 2, 256, 0, stream>>>(bufE, cursor, entries, b0, bufH);
    // h1 in bufH [M][256] bf16

    // --- layer 2 ---
    gemm2<<<(int)(M / 64), 256, 0, stream>>>(bufH, W1t, bufY);
    edge_ef_h2<<<(int)(M / 16), 256, 0, stream>>>(bufY, nn, perm, bufE);
    node_gather_mean<<<(int)(M / 16), 256, 0, stream>>>(bufE, cursor, entries, b1, meanbuf);

    // --- FC ---
    fc_k<<<1, BB * TT, 0, stream>>>(meanbuf, fcw, fcb, out, 1.0f / (float)NN);
}